// Round 9
// baseline (326.021 us; speedup 1.0000x reference)
//
#include <hip/hip_runtime.h>

#define DIN 64
#define DOUT 64
#define MAXK 32

typedef __bf16 bf16x8 __attribute__((ext_vector_type(8)));
typedef float  f32x4  __attribute__((ext_vector_type(4)));
typedef unsigned int u32x4 __attribute__((ext_vector_type(4)));

static __device__ inline unsigned short f2b(float x) {
    return __builtin_bit_cast(unsigned short, (__bf16)x);
}
static __device__ inline float b2f(unsigned short u) {
    return __uint_as_float(((unsigned int)u) << 16);
}

// ---------------- conversions ----------------

// W[k][d1][d2] fp32 -> frag-major bf16: Wt[k][t][h][lane][j]
__global__ void conv_w_kernel(const float* __restrict__ W,
                              unsigned short* __restrict__ Wt, int total) {
    int i = blockIdx.x * blockDim.x + threadIdx.x;
    if (i < total) {
        int j    = i & 7;
        int lane = (i >> 3) & 63;
        int h    = (i >> 9) & 1;
        int t    = (i >> 10) & 3;
        int k    = i >> 12;
        int col  = lane & 15;
        int quad = lane >> 4;
        int d1 = h * 32 + quad * 8 + j;
        int d2 = t * 16 + col;
        Wt[i] = f2b(W[(k * 64 + d1) * 64 + d2]);
    }
}

// ---------------- Phase A: dense transform GEMM (bf16 MFMA) ----------------
// T layout: [k][N][d2]; epilogue via LDS transpose -> coalesced 16B nt-stores.

__global__ __launch_bounds__(256) void phaseA_kernel(
    const float* __restrict__ ref,
    const unsigned short* __restrict__ Wt,
    unsigned short* __restrict__ T,
    int K0, int Nn)
{
    const int lane = threadIdx.x & 63;
    const int wid  = threadIdx.x >> 6;
    const int col  = lane & 15;
    const int quad = lane >> 4;
    const int n0   = blockIdx.x * 64 + wid * 16;
    const int row  = n0 + col;

    __shared__ __align__(16) char ldsbuf[4][16 * 144];
    char* buf = ldsbuf[wid];

    const float* rp = ref + (size_t)row * 64;
    f32x4 r0 = *reinterpret_cast<const f32x4*>(rp + quad * 8);
    f32x4 r1 = *reinterpret_cast<const f32x4*>(rp + quad * 8 + 4);
    f32x4 r2 = *reinterpret_cast<const f32x4*>(rp + 32 + quad * 8);
    f32x4 r3 = *reinterpret_cast<const f32x4*>(rp + 32 + quad * 8 + 4);
    bf16x8 b0, b1;
    #pragma unroll
    for (int i = 0; i < 4; ++i) {
        b0[i]     = (__bf16)r0[i];
        b0[4 + i] = (__bf16)r1[i];
        b1[i]     = (__bf16)r2[i];
        b1[4 + i] = (__bf16)r3[i];
    }

    const int rrow = lane >> 2;
    const int rq   = lane & 3;

    for (int k = 0; k < K0; ++k) {
        const unsigned short* Wk = Wt + (size_t)k * 4096;
        #pragma unroll
        for (int t = 0; t < 4; ++t) {
            const unsigned short* ap = Wk + (size_t)t * 1024 + lane * 8;
            bf16x8 a0 = *reinterpret_cast<const bf16x8*>(ap);
            bf16x8 a1 = *reinterpret_cast<const bf16x8*>(ap + 512);
            f32x4 c = {0.f, 0.f, 0.f, 0.f};
            c = __builtin_amdgcn_mfma_f32_16x16x32_bf16(a0, b0, c, 0, 0, 0);
            c = __builtin_amdgcn_mfma_f32_16x16x32_bf16(a1, b1, c, 0, 0, 0);
            unsigned int lo = (unsigned int)f2b(c[0]) | ((unsigned int)f2b(c[1]) << 16);
            unsigned int hi = (unsigned int)f2b(c[2]) | ((unsigned int)f2b(c[3]) << 16);
            *reinterpret_cast<uint2*>(buf + col * 144 + t * 32 + quad * 8) =
                make_uint2(lo, hi);
        }
        u32x4 v0 = *reinterpret_cast<const u32x4*>(buf + rrow * 144 + rq * 32);
        u32x4 v1 = *reinterpret_cast<const u32x4*>(buf + rrow * 144 + rq * 32 + 16);
        size_t gbase = ((size_t)k * Nn + n0 + rrow) * 64 + rq * 16;
        __builtin_nontemporal_store(v0, reinterpret_cast<u32x4*>(T + gbase));
        __builtin_nontemporal_store(v1, reinterpret_cast<u32x4*>(T + gbase + 8));
    }
}

// ---------------- 2-level query bucket sort ----------------
// Coarse bucket = q >> 8 (NB = M/256 buckets, NB <= 256); fine = q & 255.
// Payload 8B: {r | k<<16 | qlo<<21, w_bits}   (needs N<=65536, K0<=32)

__global__ void p1_hist_kernel(const int* __restrict__ eq, int E,
                               int* __restrict__ qcount) {
    __shared__ int l[256];
    l[threadIdx.x] = 0;
    __syncthreads();
    int stride = gridDim.x * blockDim.x;
    for (int i = blockIdx.x * blockDim.x + threadIdx.x; i < E; i += stride)
        atomicAdd(&l[((unsigned)eq[i]) >> 8], 1);
    __syncthreads();
    int v = l[threadIdx.x];
    if (v) atomicAdd(&qcount[threadIdx.x], v);
}

__global__ void p1_scan_kernel(const int* __restrict__ qcount,
                               int* __restrict__ gbase, int* __restrict__ gcursor,
                               int* __restrict__ qstart, int NB, int M, int E) {
    __shared__ int sh[256];
    int t = threadIdx.x;
    int v = (t < NB) ? qcount[t] : 0;
    sh[t] = v;
    __syncthreads();
    #pragma unroll
    for (int o = 1; o < 256; o <<= 1) {
        int x = (t >= o) ? sh[t - o] : 0;
        __syncthreads();
        sh[t] += x;
        __syncthreads();
    }
    int ex = sh[t] - v;
    if (t < NB) { gbase[t] = ex; gcursor[t] = ex; }
    if (t == 0) qstart[M] = E;
}

// block-aggregated scatter into coarse buckets; contiguous runs -> L2 combines.
__global__ __launch_bounds__(256) void p1_scatter_kernel(
    const int* __restrict__ eq, const int* __restrict__ er,
    const int* __restrict__ ek, const float* __restrict__ ew,
    int E, int* __restrict__ gcursor, uint2* __restrict__ tmp)
{
    __shared__ int bin[256];
    __shared__ int base[256];
    const int t = threadIdx.x;
    bin[t] = 0;
    __syncthreads();
    const int i0 = blockIdx.x * 4096;
    unsigned key[16];
    unsigned rank[16];
    uint2 pay[16];
    #pragma unroll
    for (int u = 0; u < 16; ++u) {
        int i = i0 + u * 256 + t;
        if (i < E) {
            int q = eq[i];
            unsigned b = ((unsigned)q) >> 8;
            key[u] = b;
            rank[u] = atomicAdd(&bin[b], 1);
            pay[u] = make_uint2((unsigned)er[i] | ((unsigned)ek[i] << 16) |
                                ((unsigned)(q & 255) << 21),
                                __float_as_uint(ew[i]));
        } else {
            key[u] = 0xFFFFFFFFu;
        }
    }
    __syncthreads();
    int c = bin[t];
    if (c) base[t] = atomicAdd(&gcursor[t], c);
    __syncthreads();
    #pragma unroll
    for (int u = 0; u < 16; ++u) {
        if (key[u] != 0xFFFFFFFFu)
            tmp[(size_t)base[key[u]] + rank[u]] = pay[u];
    }
}

// per-coarse-bucket fine sort + qstart emission (scatter confined to ~48KB).
__global__ __launch_bounds__(256) void p2_kernel(
    const uint2* __restrict__ tmp, const int* __restrict__ gbase,
    const int* __restrict__ qcount, uint2* __restrict__ rec,
    int* __restrict__ qstart)
{
    __shared__ int fine[256];
    __shared__ int foff[256];
    const int b = blockIdx.x;
    const int t = threadIdx.x;
    const int s = gbase[b];
    const int L = qcount[b];
    fine[t] = 0;
    __syncthreads();
    for (int i = t; i < L; i += 256)
        atomicAdd(&fine[(tmp[s + i].x >> 21) & 255], 1);
    __syncthreads();
    int v = fine[t];
    __syncthreads();
    #pragma unroll
    for (int o = 1; o < 256; o <<= 1) {
        int x = (t >= o) ? fine[t - o] : 0;
        __syncthreads();
        fine[t] += x;
        __syncthreads();
    }
    foff[t] = fine[t] - v;
    qstart[b * 256 + t] = s + foff[t];
    __syncthreads();
    fine[t] = 0;
    __syncthreads();
    for (int i = t; i < L; i += 256) {
        uint2 p = tmp[s + i];
        unsigned fb = (p.x >> 21) & 255;
        int r = atomicAdd(&fine[fb], 1);
        rec[(size_t)s + foff[fb] + r] = p;
    }
}

// ---------------- Phase B: per-query gather-accumulate (no atomics) ----------------
// v3: whole edge list loaded once per wave; statically double-buffered groups
// of 8 nontemporal T-gathers -> 8-16 loads continuously in flight.

#define PB_ISSUE(TB, WB, BASE)                                                  \
    {                                                                           \
        _Pragma("unroll")                                                       \
        for (int u = 0; u < 8; ++u) {                                           \
            unsigned mx = (unsigned)__shfl((int)rv.x, (BASE) + u);              \
            unsigned mw = (unsigned)__shfl((int)rv.y, (BASE) + u);              \
            TB[u] = __builtin_nontemporal_load(                                 \
                T + ((size_t)((mx >> 16) & 31) * Nn + (mx & 0xFFFFu)) * 64 + lane); \
            WB[u] = __uint_as_float(mw);                                        \
        }                                                                       \
    }

#define PB_CONSUME(TB, WB)                                                      \
    {                                                                           \
        _Pragma("unroll")                                                       \
        for (int u = 0; u < 8; ++u) acc = fmaf(WB[u], b2f(TB[u]), acc);         \
    }

__global__ __launch_bounds__(256) void phaseB_kernel(
    const unsigned short* __restrict__ T,    // [K0][N][64] bf16
    const uint2* __restrict__ rec,
    const int* __restrict__ qstart,
    float* __restrict__ out, int Nn)
{
    const int lane = threadIdx.x & 63;
    const int wid  = threadIdx.x >> 6;
    const int q    = blockIdx.x * 4 + wid;

    int beg = qstart[q];
    int end = qstart[q + 1];
    int cnt = end - beg;
    float acc = 0.f;

    if (cnt > 0 && cnt <= 64) {
        // lanes >= cnt hold rv = 0 -> weight 0, address T[0] (safe pad)
        uint2 rv = make_uint2(0u, 0u);
        if (lane < cnt) rv = rec[beg + lane];
        const int ng = (cnt + 7) >> 3;

        unsigned short tA[8], tB[8];
        float wA[8], wB[8];

        PB_ISSUE(tA, wA, 0)
        for (int g = 0; g < ng; g += 2) {
            if (g + 1 < ng) PB_ISSUE(tB, wB, (g + 1) * 8)
            PB_CONSUME(tA, wA)
            if (g + 1 >= ng) break;
            if (g + 2 < ng) PB_ISSUE(tA, wA, (g + 2) * 8)
            PB_CONSUME(tB, wB)
        }
    } else if (cnt > 64) {
        for (int j = beg; j < end; ++j) {
            uint2 v0 = rec[j];
            unsigned m0 = __builtin_amdgcn_readfirstlane(v0.x);
            float w0 = __uint_as_float(__builtin_amdgcn_readfirstlane(v0.y));
            acc = fmaf(w0,
                       b2f(T[((size_t)((m0 >> 16) & 31) * Nn + (m0 & 0xFFFFu)) * 64 + lane]),
                       acc);
        }
    }
    out[(size_t)q * 64 + lane] = acc;
}

// ================= fallback path (round-1): kernel-bucketed fp32 =================

__global__ void hist_kernel(const int* __restrict__ ek, int E, int* __restrict__ counts) {
    __shared__ int l[MAXK];
    if (threadIdx.x < MAXK) l[threadIdx.x] = 0;
    __syncthreads();
    int stride = gridDim.x * blockDim.x;
    for (int i = blockIdx.x * blockDim.x + threadIdx.x; i < E; i += stride)
        atomicAdd(&l[ek[i]], 1);
    __syncthreads();
    if (threadIdx.x < MAXK) {
        int v = l[threadIdx.x];
        if (v) atomicAdd(&counts[threadIdx.x], v);
    }
}

__global__ void scan_kernel(const int* __restrict__ counts, int K,
                            int* __restrict__ start, int* __restrict__ cursor) {
    if (threadIdx.x == 0 && blockIdx.x == 0) {
        int acc = 0;
        for (int k = 0; k < K; ++k) {
            start[k] = acc;
            cursor[k] = acc;
            acc += counts[k];
        }
    }
}

__global__ void scatter_kernel(const int* __restrict__ ek, int E,
                               int* __restrict__ cursor, int* __restrict__ sorted) {
    __shared__ int lcnt[MAXK], lbase[MAXK], lpos[MAXK];
    if (threadIdx.x < MAXK) { lcnt[threadIdx.x] = 0; lpos[threadIdx.x] = 0; }
    __syncthreads();
    int i = blockIdx.x * blockDim.x + threadIdx.x;
    int k = 0;
    bool valid = (i < E);
    if (valid) { k = ek[i]; atomicAdd(&lcnt[k], 1); }
    __syncthreads();
    if (threadIdx.x < MAXK) {
        int v = lcnt[threadIdx.x];
        if (v) lbase[threadIdx.x] = atomicAdd(&cursor[threadIdx.x], v);
    }
    __syncthreads();
    if (valid) {
        int slot = lbase[k] + atomicAdd(&lpos[k], 1);
        sorted[slot] = i;
    }
}

__global__ __launch_bounds__(256) void mp_bucket_kernel(
    const float* __restrict__ W, const float* __restrict__ ref,
    const int* __restrict__ e_ref, const int* __restrict__ e_query,
    const float* __restrict__ e_weight, const int* __restrict__ sorted,
    const int* __restrict__ start, const int* __restrict__ counts,
    float* __restrict__ out)
{
    const int k = blockIdx.y;
    const int lane = threadIdx.x & 63;
    const int wid = threadIdx.x >> 6;

    float wreg[DIN];
    const float* Wk = W + k * DIN * DOUT;
    #pragma unroll
    for (int d = 0; d < DIN; ++d) wreg[d] = Wk[d * DOUT + lane];

    const int s = start[k];
    const int c = counts[k];
    const int nwaves = gridDim.x * 4;

    for (int i = blockIdx.x * 4 + wid; i < c; i += nwaves) {
        int eid = __builtin_amdgcn_readfirstlane(sorted[s + i]);
        int r = e_ref[eid];
        int q = e_query[eid];
        float w = e_weight[eid];
        const float* row = ref + r * DIN;
        float a0 = 0.f, a1 = 0.f, a2 = 0.f, a3 = 0.f;
        #pragma unroll
        for (int d = 0; d < DIN; d += 4) {
            a0 += row[d + 0] * wreg[d + 0];
            a1 += row[d + 1] * wreg[d + 1];
            a2 += row[d + 2] * wreg[d + 2];
            a3 += row[d + 3] * wreg[d + 3];
        }
        atomicAdd(&out[q * DOUT + lane], ((a0 + a1) + (a2 + a3)) * w);
    }
}

// =================================================================================

extern "C" void kernel_launch(void* const* d_in, const int* in_sizes, int n_in,
                              void* d_out, int out_size, void* d_ws, size_t ws_size,
                              hipStream_t stream) {
    const float* W        = (const float*)d_in[0];   // [K0, 64, 64]
    const float* ref      = (const float*)d_in[1];   // [N, 64]
    const int*   e_kernel = (const int*)d_in[2];     // [E]
    const int*   e_ref    = (const int*)d_in[3];     // [E]
    const int*   e_query  = (const int*)d_in[4];     // [E]
    const float* e_weight = (const float*)d_in[6];   // [E]

    const int K0 = in_sizes[0] / (DIN * DOUT);
    const int N  = in_sizes[1] / DIN;
    const int E  = in_sizes[2];
    const int M  = out_size / DOUT;
    const int KD = K0 * 64;
    const int NB = M / 256;          // coarse buckets

    float* out = (float*)d_out;

    // ---- plan A workspace carve ----
    size_t off = 0;
    auto alloc = [&](size_t bytes, size_t align) {
        off = (off + align - 1) / align * align;
        size_t r = off; off += bytes; return r;
    };
    size_t o_tmp     = alloc((size_t)E * 8, 16);
    size_t o_rec     = alloc((size_t)E * 8, 16);
    size_t o_qstart  = alloc((size_t)(M + 1) * 4, 4);
    size_t o_qcount  = alloc(256 * 4, 4);
    size_t o_gbase   = alloc(256 * 4, 4);
    size_t o_gcursor = alloc(256 * 4, 4);
    size_t o_wt      = alloc((size_t)K0 * 4096 * 2, 16);
    size_t o_T       = alloc((size_t)N * KD * 2, 16);
    size_t needA = off;

    bool planA_ok = (ws_size >= needA) && (M % 256 == 0) && (NB >= 1) && (NB <= 256) &&
                    (N % 64 == 0) && (N <= 65536) && (K0 <= 32);

    if (planA_ok) {
        char* ws = (char*)d_ws;
        uint2* tmp           = (uint2*)(ws + o_tmp);
        uint2* rec           = (uint2*)(ws + o_rec);
        int*  qstart         = (int*)(ws + o_qstart);
        int*  qcount         = (int*)(ws + o_qcount);
        int*  gbase          = (int*)(ws + o_gbase);
        int*  gcursor        = (int*)(ws + o_gcursor);
        unsigned short* Wt   = (unsigned short*)(ws + o_wt);
        unsigned short* T    = (unsigned short*)(ws + o_T);

        conv_w_kernel<<<(K0 * 4096 + 255) / 256, 256, 0, stream>>>(W, Wt, K0 * 4096);

        hipMemsetAsync(qcount, 0, 256 * 4, stream);
        p1_hist_kernel<<<512, 256, 0, stream>>>(e_query, E, qcount);
        p1_scan_kernel<<<1, 256, 0, stream>>>(qcount, gbase, gcursor, qstart, NB, M, E);
        p1_scatter_kernel<<<(E + 4095) / 4096, 256, 0, stream>>>(e_query, e_ref, e_kernel,
                                                                 e_weight, E, gcursor, tmp);
        p2_kernel<<<NB, 256, 0, stream>>>(tmp, gbase, qcount, rec, qstart);

        phaseA_kernel<<<N / 64, 256, 0, stream>>>(ref, Wt, T, K0, N);

        phaseB_kernel<<<M / 4, 256, 0, stream>>>(T, rec, qstart, out, N);
    } else {
        hipMemsetAsync(out, 0, (size_t)out_size * sizeof(float), stream);
        size_t needB = (size_t)(96 + E) * sizeof(int);
        if (ws_size >= needB) {
            int* ws_i   = (int*)d_ws;
            int* counts = ws_i;
            int* start  = ws_i + 32;
            int* cursor = ws_i + 64;
            int* sorted = ws_i + 96;
            hipMemsetAsync(counts, 0, 96 * sizeof(int), stream);
            hist_kernel<<<512, 256, 0, stream>>>(e_kernel, E, counts);
            scan_kernel<<<1, 64, 0, stream>>>(counts, K0, start, cursor);
            scatter_kernel<<<(E + 255) / 256, 256, 0, stream>>>(e_kernel, E, cursor, sorted);
            dim3 grid(64, K0);
            mp_bucket_kernel<<<grid, 256, 0, stream>>>(W, ref, e_ref, e_query, e_weight,
                                                       sorted, start, counts, out);
        }
    }
}

// Round 10
// 299.664 us; speedup vs baseline: 1.0880x; 1.0880x over previous
//
#include <hip/hip_runtime.h>

#define DIN 64
#define DOUT 64
#define MAXK 32

typedef __bf16 bf16x8 __attribute__((ext_vector_type(8)));
typedef float  f32x4  __attribute__((ext_vector_type(4)));
typedef unsigned int u32x4 __attribute__((ext_vector_type(4)));

static __device__ inline unsigned short f2b(float x) {
    return __builtin_bit_cast(unsigned short, (__bf16)x);
}
static __device__ inline float b2f(unsigned short u) {
    return __uint_as_float(((unsigned int)u) << 16);
}

// ---------------- conversions ----------------

// W[k][d1][d2] fp32 -> frag-major bf16: Wt[k][t][h][lane][j]
__global__ void conv_w_kernel(const float* __restrict__ W,
                              unsigned short* __restrict__ Wt, int total) {
    int i = blockIdx.x * blockDim.x + threadIdx.x;
    if (i < total) {
        int j    = i & 7;
        int lane = (i >> 3) & 63;
        int h    = (i >> 9) & 1;
        int t    = (i >> 10) & 3;
        int k    = i >> 12;
        int col  = lane & 15;
        int quad = lane >> 4;
        int d1 = h * 32 + quad * 8 + j;
        int d2 = t * 16 + col;
        Wt[i] = f2b(W[(k * 64 + d1) * 64 + d2]);
    }
}

// ---------------- Phase A: dense transform GEMM (bf16 MFMA) ----------------
// T layout: [k][N][d2]; epilogue via LDS transpose -> coalesced 16B stores.
// NOTE: stores must be CACHED (not nt): v0/v1 of one lane interleave at 16B
// granularity; L2 merges them into full lines. nt caused 1.5x write amp (r9).

__global__ __launch_bounds__(256) void phaseA_kernel(
    const float* __restrict__ ref,
    const unsigned short* __restrict__ Wt,
    unsigned short* __restrict__ T,
    int K0, int Nn)
{
    const int lane = threadIdx.x & 63;
    const int wid  = threadIdx.x >> 6;
    const int col  = lane & 15;
    const int quad = lane >> 4;
    const int n0   = blockIdx.x * 64 + wid * 16;
    const int row  = n0 + col;

    __shared__ __align__(16) char ldsbuf[4][16 * 144];
    char* buf = ldsbuf[wid];

    const float* rp = ref + (size_t)row * 64;
    f32x4 r0 = *reinterpret_cast<const f32x4*>(rp + quad * 8);
    f32x4 r1 = *reinterpret_cast<const f32x4*>(rp + quad * 8 + 4);
    f32x4 r2 = *reinterpret_cast<const f32x4*>(rp + 32 + quad * 8);
    f32x4 r3 = *reinterpret_cast<const f32x4*>(rp + 32 + quad * 8 + 4);
    bf16x8 b0, b1;
    #pragma unroll
    for (int i = 0; i < 4; ++i) {
        b0[i]     = (__bf16)r0[i];
        b0[4 + i] = (__bf16)r1[i];
        b1[i]     = (__bf16)r2[i];
        b1[4 + i] = (__bf16)r3[i];
    }

    const int rrow = lane >> 2;
    const int rq   = lane & 3;

    for (int k = 0; k < K0; ++k) {
        const unsigned short* Wk = Wt + (size_t)k * 4096;
        #pragma unroll
        for (int t = 0; t < 4; ++t) {
            const unsigned short* ap = Wk + (size_t)t * 1024 + lane * 8;
            bf16x8 a0 = *reinterpret_cast<const bf16x8*>(ap);
            bf16x8 a1 = *reinterpret_cast<const bf16x8*>(ap + 512);
            f32x4 c = {0.f, 0.f, 0.f, 0.f};
            c = __builtin_amdgcn_mfma_f32_16x16x32_bf16(a0, b0, c, 0, 0, 0);
            c = __builtin_amdgcn_mfma_f32_16x16x32_bf16(a1, b1, c, 0, 0, 0);
            unsigned int lo = (unsigned int)f2b(c[0]) | ((unsigned int)f2b(c[1]) << 16);
            unsigned int hi = (unsigned int)f2b(c[2]) | ((unsigned int)f2b(c[3]) << 16);
            *reinterpret_cast<uint2*>(buf + col * 144 + t * 32 + quad * 8) =
                make_uint2(lo, hi);
        }
        u32x4 v0 = *reinterpret_cast<const u32x4*>(buf + rrow * 144 + rq * 32);
        u32x4 v1 = *reinterpret_cast<const u32x4*>(buf + rrow * 144 + rq * 32 + 16);
        size_t gbase = ((size_t)k * Nn + n0 + rrow) * 64 + rq * 16;
        *reinterpret_cast<u32x4*>(T + gbase)     = v0;
        *reinterpret_cast<u32x4*>(T + gbase + 8) = v1;
    }
}

// ---------------- 2-level query bucket sort ----------------
// Coarse bucket = q >> 8 (NB = M/256 buckets, NB <= 256); fine = q & 255.
// Payload 8B: {r | k<<16 | qlo<<21, w_bits}   (needs N<=65536, K0<=32)

__global__ void p1_hist_kernel(const int* __restrict__ eq, int E,
                               int* __restrict__ qcount) {
    __shared__ int l[256];
    l[threadIdx.x] = 0;
    __syncthreads();
    int stride = gridDim.x * blockDim.x;
    for (int i = blockIdx.x * blockDim.x + threadIdx.x; i < E; i += stride)
        atomicAdd(&l[((unsigned)eq[i]) >> 8], 1);
    __syncthreads();
    int v = l[threadIdx.x];
    if (v) atomicAdd(&qcount[threadIdx.x], v);
}

__global__ void p1_scan_kernel(const int* __restrict__ qcount,
                               int* __restrict__ gbase, int* __restrict__ gcursor,
                               int* __restrict__ qstart, int NB, int M, int E) {
    __shared__ int sh[256];
    int t = threadIdx.x;
    int v = (t < NB) ? qcount[t] : 0;
    sh[t] = v;
    __syncthreads();
    #pragma unroll
    for (int o = 1; o < 256; o <<= 1) {
        int x = (t >= o) ? sh[t - o] : 0;
        __syncthreads();
        sh[t] += x;
        __syncthreads();
    }
    int ex = sh[t] - v;
    if (t < NB) { gbase[t] = ex; gcursor[t] = ex; }
    if (t == 0) qstart[M] = E;
}

// block-aggregated scatter into coarse buckets; contiguous runs -> L2 combines.
__global__ __launch_bounds__(256) void p1_scatter_kernel(
    const int* __restrict__ eq, const int* __restrict__ er,
    const int* __restrict__ ek, const float* __restrict__ ew,
    int E, int* __restrict__ gcursor, uint2* __restrict__ tmp)
{
    __shared__ int bin[256];
    __shared__ int base[256];
    const int t = threadIdx.x;
    bin[t] = 0;
    __syncthreads();
    const int i0 = blockIdx.x * 4096;
    unsigned key[16];
    unsigned rank[16];
    uint2 pay[16];
    #pragma unroll
    for (int u = 0; u < 16; ++u) {
        int i = i0 + u * 256 + t;
        if (i < E) {
            int q = eq[i];
            unsigned b = ((unsigned)q) >> 8;
            key[u] = b;
            rank[u] = atomicAdd(&bin[b], 1);
            pay[u] = make_uint2((unsigned)er[i] | ((unsigned)ek[i] << 16) |
                                ((unsigned)(q & 255) << 21),
                                __float_as_uint(ew[i]));
        } else {
            key[u] = 0xFFFFFFFFu;
        }
    }
    __syncthreads();
    int c = bin[t];
    if (c) base[t] = atomicAdd(&gcursor[t], c);
    __syncthreads();
    #pragma unroll
    for (int u = 0; u < 16; ++u) {
        if (key[u] != 0xFFFFFFFFu)
            tmp[(size_t)base[key[u]] + rank[u]] = pay[u];
    }
}

// per-coarse-bucket fine sort + qstart emission (scatter confined to ~48KB).
__global__ __launch_bounds__(256) void p2_kernel(
    const uint2* __restrict__ tmp, const int* __restrict__ gbase,
    const int* __restrict__ qcount, uint2* __restrict__ rec,
    int* __restrict__ qstart)
{
    __shared__ int fine[256];
    __shared__ int foff[256];
    const int b = blockIdx.x;
    const int t = threadIdx.x;
    const int s = gbase[b];
    const int L = qcount[b];
    fine[t] = 0;
    __syncthreads();
    for (int i = t; i < L; i += 256)
        atomicAdd(&fine[(tmp[s + i].x >> 21) & 255], 1);
    __syncthreads();
    int v = fine[t];
    __syncthreads();
    #pragma unroll
    for (int o = 1; o < 256; o <<= 1) {
        int x = (t >= o) ? fine[t - o] : 0;
        __syncthreads();
        fine[t] += x;
        __syncthreads();
    }
    foff[t] = fine[t] - v;
    qstart[b * 256 + t] = s + foff[t];
    __syncthreads();
    fine[t] = 0;
    __syncthreads();
    for (int i = t; i < L; i += 256) {
        uint2 p = tmp[s + i];
        unsigned fb = (p.x >> 21) & 255;
        int r = atomicAdd(&fine[fb], 1);
        rec[(size_t)s + foff[fb] + r] = p;
    }
}

// ---------------- Phase B: per-query gather-accumulate (no atomics) ----------------
// v3: whole edge list loaded once per wave; statically double-buffered groups
// of 8 nontemporal T-gathers -> 8-16 loads continuously in flight.

#define PB_ISSUE(TB, WB, BASE)                                                  \
    {                                                                           \
        _Pragma("unroll")                                                       \
        for (int u = 0; u < 8; ++u) {                                           \
            unsigned mx = (unsigned)__shfl((int)rv.x, (BASE) + u);              \
            unsigned mw = (unsigned)__shfl((int)rv.y, (BASE) + u);              \
            TB[u] = __builtin_nontemporal_load(                                 \
                T + ((size_t)((mx >> 16) & 31) * Nn + (mx & 0xFFFFu)) * 64 + lane); \
            WB[u] = __uint_as_float(mw);                                        \
        }                                                                       \
    }

#define PB_CONSUME(TB, WB)                                                      \
    {                                                                           \
        _Pragma("unroll")                                                       \
        for (int u = 0; u < 8; ++u) acc = fmaf(WB[u], b2f(TB[u]), acc);         \
    }

__global__ __launch_bounds__(256) void phaseB_kernel(
    const unsigned short* __restrict__ T,    // [K0][N][64] bf16
    const uint2* __restrict__ rec,
    const int* __restrict__ qstart,
    float* __restrict__ out, int Nn)
{
    const int lane = threadIdx.x & 63;
    const int wid  = threadIdx.x >> 6;
    const int q    = blockIdx.x * 4 + wid;

    int beg = qstart[q];
    int end = qstart[q + 1];
    int cnt = end - beg;
    float acc = 0.f;

    if (cnt > 0 && cnt <= 64) {
        // lanes >= cnt hold rv = 0 -> weight 0, address T[0] (safe pad)
        uint2 rv = make_uint2(0u, 0u);
        if (lane < cnt) rv = rec[beg + lane];
        const int ng = (cnt + 7) >> 3;

        unsigned short tA[8], tB[8];
        float wA[8], wB[8];

        PB_ISSUE(tA, wA, 0)
        for (int g = 0; g < ng; g += 2) {
            if (g + 1 < ng) PB_ISSUE(tB, wB, (g + 1) * 8)
            PB_CONSUME(tA, wA)
            if (g + 1 >= ng) break;
            if (g + 2 < ng) PB_ISSUE(tA, wA, (g + 2) * 8)
            PB_CONSUME(tB, wB)
        }
    } else if (cnt > 64) {
        for (int j = beg; j < end; ++j) {
            uint2 v0 = rec[j];
            unsigned m0 = __builtin_amdgcn_readfirstlane(v0.x);
            float w0 = __uint_as_float(__builtin_amdgcn_readfirstlane(v0.y));
            acc = fmaf(w0,
                       b2f(T[((size_t)((m0 >> 16) & 31) * Nn + (m0 & 0xFFFFu)) * 64 + lane]),
                       acc);
        }
    }
    out[(size_t)q * 64 + lane] = acc;
}

// ================= fallback path (round-1): kernel-bucketed fp32 =================

__global__ void hist_kernel(const int* __restrict__ ek, int E, int* __restrict__ counts) {
    __shared__ int l[MAXK];
    if (threadIdx.x < MAXK) l[threadIdx.x] = 0;
    __syncthreads();
    int stride = gridDim.x * blockDim.x;
    for (int i = blockIdx.x * blockDim.x + threadIdx.x; i < E; i += stride)
        atomicAdd(&l[ek[i]], 1);
    __syncthreads();
    if (threadIdx.x < MAXK) {
        int v = l[threadIdx.x];
        if (v) atomicAdd(&counts[threadIdx.x], v);
    }
}

__global__ void scan_kernel(const int* __restrict__ counts, int K,
                            int* __restrict__ start, int* __restrict__ cursor) {
    if (threadIdx.x == 0 && blockIdx.x == 0) {
        int acc = 0;
        for (int k = 0; k < K; ++k) {
            start[k] = acc;
            cursor[k] = acc;
            acc += counts[k];
        }
    }
}

__global__ void scatter_kernel(const int* __restrict__ ek, int E,
                               int* __restrict__ cursor, int* __restrict__ sorted) {
    __shared__ int lcnt[MAXK], lbase[MAXK], lpos[MAXK];
    if (threadIdx.x < MAXK) { lcnt[threadIdx.x] = 0; lpos[threadIdx.x] = 0; }
    __syncthreads();
    int i = blockIdx.x * blockDim.x + threadIdx.x;
    int k = 0;
    bool valid = (i < E);
    if (valid) { k = ek[i]; atomicAdd(&lcnt[k], 1); }
    __syncthreads();
    if (threadIdx.x < MAXK) {
        int v = lcnt[threadIdx.x];
        if (v) lbase[threadIdx.x] = atomicAdd(&cursor[threadIdx.x], v);
    }
    __syncthreads();
    if (valid) {
        int slot = lbase[k] + atomicAdd(&lpos[k], 1);
        sorted[slot] = i;
    }
}

__global__ __launch_bounds__(256) void mp_bucket_kernel(
    const float* __restrict__ W, const float* __restrict__ ref,
    const int* __restrict__ e_ref, const int* __restrict__ e_query,
    const float* __restrict__ e_weight, const int* __restrict__ sorted,
    const int* __restrict__ start, const int* __restrict__ counts,
    float* __restrict__ out)
{
    const int k = blockIdx.y;
    const int lane = threadIdx.x & 63;
    const int wid = threadIdx.x >> 6;

    float wreg[DIN];
    const float* Wk = W + k * DIN * DOUT;
    #pragma unroll
    for (int d = 0; d < DIN; ++d) wreg[d] = Wk[d * DOUT + lane];

    const int s = start[k];
    const int c = counts[k];
    const int nwaves = gridDim.x * 4;

    for (int i = blockIdx.x * 4 + wid; i < c; i += nwaves) {
        int eid = __builtin_amdgcn_readfirstlane(sorted[s + i]);
        int r = e_ref[eid];
        int q = e_query[eid];
        float w = e_weight[eid];
        const float* row = ref + r * DIN;
        float a0 = 0.f, a1 = 0.f, a2 = 0.f, a3 = 0.f;
        #pragma unroll
        for (int d = 0; d < DIN; d += 4) {
            a0 += row[d + 0] * wreg[d + 0];
            a1 += row[d + 1] * wreg[d + 1];
            a2 += row[d + 2] * wreg[d + 2];
            a3 += row[d + 3] * wreg[d + 3];
        }
        atomicAdd(&out[q * DOUT + lane], ((a0 + a1) + (a2 + a3)) * w);
    }
}

// =================================================================================

extern "C" void kernel_launch(void* const* d_in, const int* in_sizes, int n_in,
                              void* d_out, int out_size, void* d_ws, size_t ws_size,
                              hipStream_t stream) {
    const float* W        = (const float*)d_in[0];   // [K0, 64, 64]
    const float* ref      = (const float*)d_in[1];   // [N, 64]
    const int*   e_kernel = (const int*)d_in[2];     // [E]
    const int*   e_ref    = (const int*)d_in[3];     // [E]
    const int*   e_query  = (const int*)d_in[4];     // [E]
    const float* e_weight = (const float*)d_in[6];   // [E]

    const int K0 = in_sizes[0] / (DIN * DOUT);
    const int N  = in_sizes[1] / DIN;
    const int E  = in_sizes[2];
    const int M  = out_size / DOUT;
    const int KD = K0 * 64;
    const int NB = M / 256;          // coarse buckets

    float* out = (float*)d_out;

    // ---- plan A workspace carve ----
    size_t off = 0;
    auto alloc = [&](size_t bytes, size_t align) {
        off = (off + align - 1) / align * align;
        size_t r = off; off += bytes; return r;
    };
    size_t o_tmp     = alloc((size_t)E * 8, 16);
    size_t o_rec     = alloc((size_t)E * 8, 16);
    size_t o_qstart  = alloc((size_t)(M + 1) * 4, 4);
    size_t o_qcount  = alloc(256 * 4, 4);
    size_t o_gbase   = alloc(256 * 4, 4);
    size_t o_gcursor = alloc(256 * 4, 4);
    size_t o_wt      = alloc((size_t)K0 * 4096 * 2, 16);
    size_t o_T       = alloc((size_t)N * KD * 2, 16);
    size_t needA = off;

    bool planA_ok = (ws_size >= needA) && (M % 256 == 0) && (NB >= 1) && (NB <= 256) &&
                    (N % 64 == 0) && (N <= 65536) && (K0 <= 32);

    if (planA_ok) {
        char* ws = (char*)d_ws;
        uint2* tmp           = (uint2*)(ws + o_tmp);
        uint2* rec           = (uint2*)(ws + o_rec);
        int*  qstart         = (int*)(ws + o_qstart);
        int*  qcount         = (int*)(ws + o_qcount);
        int*  gbase          = (int*)(ws + o_gbase);
        int*  gcursor        = (int*)(ws + o_gcursor);
        unsigned short* Wt   = (unsigned short*)(ws + o_wt);
        unsigned short* T    = (unsigned short*)(ws + o_T);

        conv_w_kernel<<<(K0 * 4096 + 255) / 256, 256, 0, stream>>>(W, Wt, K0 * 4096);

        hipMemsetAsync(qcount, 0, 256 * 4, stream);
        p1_hist_kernel<<<512, 256, 0, stream>>>(e_query, E, qcount);
        p1_scan_kernel<<<1, 256, 0, stream>>>(qcount, gbase, gcursor, qstart, NB, M, E);
        p1_scatter_kernel<<<(E + 4095) / 4096, 256, 0, stream>>>(e_query, e_ref, e_kernel,
                                                                 e_weight, E, gcursor, tmp);
        p2_kernel<<<NB, 256, 0, stream>>>(tmp, gbase, qcount, rec, qstart);

        phaseA_kernel<<<N / 64, 256, 0, stream>>>(ref, Wt, T, K0, N);

        phaseB_kernel<<<M / 4, 256, 0, stream>>>(T, rec, qstart, out, N);
    } else {
        hipMemsetAsync(out, 0, (size_t)out_size * sizeof(float), stream);
        size_t needB = (size_t)(96 + E) * sizeof(int);
        if (ws_size >= needB) {
            int* ws_i   = (int*)d_ws;
            int* counts = ws_i;
            int* start  = ws_i + 32;
            int* cursor = ws_i + 64;
            int* sorted = ws_i + 96;
            hipMemsetAsync(counts, 0, 96 * sizeof(int), stream);
            hist_kernel<<<512, 256, 0, stream>>>(e_kernel, E, counts);
            scan_kernel<<<1, 64, 0, stream>>>(counts, K0, start, cursor);
            scatter_kernel<<<(E + 255) / 256, 256, 0, stream>>>(e_kernel, E, cursor, sorted);
            dim3 grid(64, K0);
            mp_bucket_kernel<<<grid, 256, 0, stream>>>(W, ref, e_ref, e_query, e_weight,
                                                       sorted, start, counts, out);
        }
    }
}

// Round 11
// 279.613 us; speedup vs baseline: 1.1660x; 1.0717x over previous
//
#include <hip/hip_runtime.h>

#define DIN 64
#define DOUT 64
#define MAXK 32

typedef __bf16 bf16x8 __attribute__((ext_vector_type(8)));
typedef float  f32x4  __attribute__((ext_vector_type(4)));
typedef unsigned int u32x4 __attribute__((ext_vector_type(4)));

static __device__ inline unsigned short f2b(float x) {
    return __builtin_bit_cast(unsigned short, (__bf16)x);
}
static __device__ inline float b2f(unsigned short u) {
    return __uint_as_float(((unsigned int)u) << 16);
}

// ---------------- conversions ----------------

// W[k][d1][d2] fp32 -> frag-major bf16: Wt[k][t][h][lane][j]
// Also zeroes qcount[256] (fused memset: saves one dispatch).
__global__ void conv_w_kernel(const float* __restrict__ W,
                              unsigned short* __restrict__ Wt, int total,
                              int* __restrict__ qcount) {
    int i = blockIdx.x * blockDim.x + threadIdx.x;
    if (i < 256) qcount[i] = 0;
    if (i < total) {
        int j    = i & 7;
        int lane = (i >> 3) & 63;
        int h    = (i >> 9) & 1;
        int t    = (i >> 10) & 3;
        int k    = i >> 12;
        int col  = lane & 15;
        int quad = lane >> 4;
        int d1 = h * 32 + quad * 8 + j;
        int d2 = t * 16 + col;
        Wt[i] = f2b(W[(k * 64 + d1) * 64 + d2]);
    }
}

// ---------------- Phase A: dense transform GEMM (bf16 MFMA) ----------------
// T layout: [k][N][d2]; epilogue via LDS transpose -> coalesced 16B stores.
// Stores must be CACHED (not nt): lane's v0/v1 interleave at 16B granularity;
// L2 merges into full lines. nt caused 1.5x write amp (round 9: 236->350MB).

__global__ __launch_bounds__(256) void phaseA_kernel(
    const float* __restrict__ ref,
    const unsigned short* __restrict__ Wt,
    unsigned short* __restrict__ T,
    int K0, int Nn)
{
    const int lane = threadIdx.x & 63;
    const int wid  = threadIdx.x >> 6;
    const int col  = lane & 15;
    const int quad = lane >> 4;
    const int n0   = blockIdx.x * 64 + wid * 16;
    const int row  = n0 + col;

    __shared__ __align__(16) char ldsbuf[4][16 * 144];
    char* buf = ldsbuf[wid];

    const float* rp = ref + (size_t)row * 64;
    f32x4 r0 = *reinterpret_cast<const f32x4*>(rp + quad * 8);
    f32x4 r1 = *reinterpret_cast<const f32x4*>(rp + quad * 8 + 4);
    f32x4 r2 = *reinterpret_cast<const f32x4*>(rp + 32 + quad * 8);
    f32x4 r3 = *reinterpret_cast<const f32x4*>(rp + 32 + quad * 8 + 4);
    bf16x8 b0, b1;
    #pragma unroll
    for (int i = 0; i < 4; ++i) {
        b0[i]     = (__bf16)r0[i];
        b0[4 + i] = (__bf16)r1[i];
        b1[i]     = (__bf16)r2[i];
        b1[4 + i] = (__bf16)r3[i];
    }

    const int rrow = lane >> 2;
    const int rq   = lane & 3;

    for (int k = 0; k < K0; ++k) {
        const unsigned short* Wk = Wt + (size_t)k * 4096;
        #pragma unroll
        for (int t = 0; t < 4; ++t) {
            const unsigned short* ap = Wk + (size_t)t * 1024 + lane * 8;
            bf16x8 a0 = *reinterpret_cast<const bf16x8*>(ap);
            bf16x8 a1 = *reinterpret_cast<const bf16x8*>(ap + 512);
            f32x4 c = {0.f, 0.f, 0.f, 0.f};
            c = __builtin_amdgcn_mfma_f32_16x16x32_bf16(a0, b0, c, 0, 0, 0);
            c = __builtin_amdgcn_mfma_f32_16x16x32_bf16(a1, b1, c, 0, 0, 0);
            unsigned int lo = (unsigned int)f2b(c[0]) | ((unsigned int)f2b(c[1]) << 16);
            unsigned int hi = (unsigned int)f2b(c[2]) | ((unsigned int)f2b(c[3]) << 16);
            *reinterpret_cast<uint2*>(buf + col * 144 + t * 32 + quad * 8) =
                make_uint2(lo, hi);
        }
        u32x4 v0 = *reinterpret_cast<const u32x4*>(buf + rrow * 144 + rq * 32);
        u32x4 v1 = *reinterpret_cast<const u32x4*>(buf + rrow * 144 + rq * 32 + 16);
        size_t gbase = ((size_t)k * Nn + n0 + rrow) * 64 + rq * 16;
        *reinterpret_cast<u32x4*>(T + gbase)     = v0;
        *reinterpret_cast<u32x4*>(T + gbase + 8) = v1;
    }
}

// ---------------- 2-level query bucket sort ----------------
// Coarse bucket = q >> 8 (NB = M/256 buckets, NB <= 256); fine = q & 255.
// Payload 8B: {r | k<<16 | qlo<<21, w_bits}   (needs N<=65536, K0<=32)

__global__ void p1_hist_kernel(const int* __restrict__ eq, int E,
                               int* __restrict__ qcount) {
    __shared__ int l[256];
    l[threadIdx.x] = 0;
    __syncthreads();
    int stride = gridDim.x * blockDim.x;
    for (int i = blockIdx.x * blockDim.x + threadIdx.x; i < E; i += stride)
        atomicAdd(&l[((unsigned)eq[i]) >> 8], 1);
    __syncthreads();
    int v = l[threadIdx.x];
    if (v) atomicAdd(&qcount[threadIdx.x], v);
}

__global__ void p1_scan_kernel(const int* __restrict__ qcount,
                               int* __restrict__ gbase, int* __restrict__ gcursor,
                               int* __restrict__ qstart, int NB, int M, int E) {
    __shared__ int sh[256];
    int t = threadIdx.x;
    int v = (t < NB) ? qcount[t] : 0;
    sh[t] = v;
    __syncthreads();
    #pragma unroll
    for (int o = 1; o < 256; o <<= 1) {
        int x = (t >= o) ? sh[t - o] : 0;
        __syncthreads();
        sh[t] += x;
        __syncthreads();
    }
    int ex = sh[t] - v;
    if (t < NB) { gbase[t] = ex; gcursor[t] = ex; }
    if (t == 0) qstart[M] = E;
}

// block-aggregated scatter into coarse buckets; contiguous runs -> L2 combines.
__global__ __launch_bounds__(256) void p1_scatter_kernel(
    const int* __restrict__ eq, const int* __restrict__ er,
    const int* __restrict__ ek, const float* __restrict__ ew,
    int E, int* __restrict__ gcursor, uint2* __restrict__ tmp)
{
    __shared__ int bin[256];
    __shared__ int base[256];
    const int t = threadIdx.x;
    bin[t] = 0;
    __syncthreads();
    const int i0 = blockIdx.x * 4096;
    unsigned key[16];
    unsigned rank[16];
    uint2 pay[16];
    #pragma unroll
    for (int u = 0; u < 16; ++u) {
        int i = i0 + u * 256 + t;
        if (i < E) {
            int q = eq[i];
            unsigned b = ((unsigned)q) >> 8;
            key[u] = b;
            rank[u] = atomicAdd(&bin[b], 1);
            pay[u] = make_uint2((unsigned)er[i] | ((unsigned)ek[i] << 16) |
                                ((unsigned)(q & 255) << 21),
                                __float_as_uint(ew[i]));
        } else {
            key[u] = 0xFFFFFFFFu;
        }
    }
    __syncthreads();
    int c = bin[t];
    if (c) base[t] = atomicAdd(&gcursor[t], c);
    __syncthreads();
    #pragma unroll
    for (int u = 0; u < 16; ++u) {
        if (key[u] != 0xFFFFFFFFu)
            tmp[(size_t)base[key[u]] + rank[u]] = pay[u];
    }
}

// per-coarse-bucket fine sort + qstart emission (scatter confined to ~48KB).
__global__ __launch_bounds__(256) void p2_kernel(
    const uint2* __restrict__ tmp, const int* __restrict__ gbase,
    const int* __restrict__ qcount, uint2* __restrict__ rec,
    int* __restrict__ qstart)
{
    __shared__ int fine[256];
    __shared__ int foff[256];
    const int b = blockIdx.x;
    const int t = threadIdx.x;
    const int s = gbase[b];
    const int L = qcount[b];
    fine[t] = 0;
    __syncthreads();
    for (int i = t; i < L; i += 256)
        atomicAdd(&fine[(tmp[s + i].x >> 21) & 255], 1);
    __syncthreads();
    int v = fine[t];
    __syncthreads();
    #pragma unroll
    for (int o = 1; o < 256; o <<= 1) {
        int x = (t >= o) ? fine[t - o] : 0;
        __syncthreads();
        fine[t] += x;
        __syncthreads();
    }
    foff[t] = fine[t] - v;
    qstart[b * 256 + t] = s + foff[t];
    __syncthreads();
    fine[t] = 0;
    __syncthreads();
    for (int i = t; i < L; i += 256) {
        uint2 p = tmp[s + i];
        unsigned fb = (p.x >> 21) & 255;
        int r = atomicAdd(&fine[fb], 1);
        rec[(size_t)s + foff[fb] + r] = p;
    }
}

// ---------------- Phase B: per-query gather-accumulate (no atomics) ----------------
// v2 (round-7 champion, 65us @ 3.4 TB/s): wave loads its whole edge list once
// (deg<=64 fast path), shfl-broadcasts metadata, 8-deep CACHED T-gathers.
// Do NOT use nontemporal loads or deeper double-buffering: both measured
// slower (round 10: 89us @ 2.5 TB/s, same FETCH bytes).

__global__ __launch_bounds__(256) void phaseB_kernel(
    const unsigned short* __restrict__ T,    // [K0][N][64] bf16
    const uint2* __restrict__ rec,
    const int* __restrict__ qstart,
    float* __restrict__ out, int Nn)
{
    const int lane = threadIdx.x & 63;
    const int wid  = threadIdx.x >> 6;
    const int q    = blockIdx.x * 4 + wid;

    int beg = qstart[q];
    int end = qstart[q + 1];
    int cnt = end - beg;
    float acc = 0.f;

    if (cnt <= 64) {
        uint2 rv = make_uint2(0u, 0u);
        if (lane < cnt) rv = rec[beg + lane];
        int j = 0;
        for (; j + 8 <= cnt; j += 8) {
            float partial[8];
            #pragma unroll
            for (int u = 0; u < 8; ++u) {
                unsigned mx = (unsigned)__shfl((int)rv.x, j + u);
                unsigned mw = (unsigned)__shfl((int)rv.y, j + u);
                unsigned short tv =
                    T[((size_t)((mx >> 16) & 31) * Nn + (mx & 0xFFFFu)) * 64 + lane];
                partial[u] = __uint_as_float(mw) * b2f(tv);
            }
            #pragma unroll
            for (int u = 0; u < 8; ++u) acc += partial[u];
        }
        for (; j < cnt; ++j) {
            unsigned mx = (unsigned)__shfl((int)rv.x, j);
            unsigned mw = (unsigned)__shfl((int)rv.y, j);
            acc = fmaf(__uint_as_float(mw),
                       b2f(T[((size_t)((mx >> 16) & 31) * Nn + (mx & 0xFFFFu)) * 64 + lane]),
                       acc);
        }
    } else {
        for (int j = beg; j < end; ++j) {
            uint2 v0 = rec[j];
            unsigned m0 = __builtin_amdgcn_readfirstlane(v0.x);
            float w0 = __uint_as_float(__builtin_amdgcn_readfirstlane(v0.y));
            acc = fmaf(w0,
                       b2f(T[((size_t)((m0 >> 16) & 31) * Nn + (m0 & 0xFFFFu)) * 64 + lane]),
                       acc);
        }
    }
    out[(size_t)q * 64 + lane] = acc;
}

// ================= fallback path (round-1): kernel-bucketed fp32 =================

__global__ void hist_kernel(const int* __restrict__ ek, int E, int* __restrict__ counts) {
    __shared__ int l[MAXK];
    if (threadIdx.x < MAXK) l[threadIdx.x] = 0;
    __syncthreads();
    int stride = gridDim.x * blockDim.x;
    for (int i = blockIdx.x * blockDim.x + threadIdx.x; i < E; i += stride)
        atomicAdd(&l[ek[i]], 1);
    __syncthreads();
    if (threadIdx.x < MAXK) {
        int v = l[threadIdx.x];
        if (v) atomicAdd(&counts[threadIdx.x], v);
    }
}

__global__ void scan_kernel(const int* __restrict__ counts, int K,
                            int* __restrict__ start, int* __restrict__ cursor) {
    if (threadIdx.x == 0 && blockIdx.x == 0) {
        int acc = 0;
        for (int k = 0; k < K; ++k) {
            start[k] = acc;
            cursor[k] = acc;
            acc += counts[k];
        }
    }
}

__global__ void scatter_kernel(const int* __restrict__ ek, int E,
                               int* __restrict__ cursor, int* __restrict__ sorted) {
    __shared__ int lcnt[MAXK], lbase[MAXK], lpos[MAXK];
    if (threadIdx.x < MAXK) { lcnt[threadIdx.x] = 0; lpos[threadIdx.x] = 0; }
    __syncthreads();
    int i = blockIdx.x * blockDim.x + threadIdx.x;
    int k = 0;
    bool valid = (i < E);
    if (valid) { k = ek[i]; atomicAdd(&lcnt[k], 1); }
    __syncthreads();
    if (threadIdx.x < MAXK) {
        int v = lcnt[threadIdx.x];
        if (v) lbase[threadIdx.x] = atomicAdd(&cursor[threadIdx.x], v);
    }
    __syncthreads();
    if (valid) {
        int slot = lbase[k] + atomicAdd(&lpos[k], 1);
        sorted[slot] = i;
    }
}

__global__ __launch_bounds__(256) void mp_bucket_kernel(
    const float* __restrict__ W, const float* __restrict__ ref,
    const int* __restrict__ e_ref, const int* __restrict__ e_query,
    const float* __restrict__ e_weight, const int* __restrict__ sorted,
    const int* __restrict__ start, const int* __restrict__ counts,
    float* __restrict__ out)
{
    const int k = blockIdx.y;
    const int lane = threadIdx.x & 63;
    const int wid = threadIdx.x >> 6;

    float wreg[DIN];
    const float* Wk = W + k * DIN * DOUT;
    #pragma unroll
    for (int d = 0; d < DIN; ++d) wreg[d] = Wk[d * DOUT + lane];

    const int s = start[k];
    const int c = counts[k];
    const int nwaves = gridDim.x * 4;

    for (int i = blockIdx.x * 4 + wid; i < c; i += nwaves) {
        int eid = __builtin_amdgcn_readfirstlane(sorted[s + i]);
        int r = e_ref[eid];
        int q = e_query[eid];
        float w = e_weight[eid];
        const float* row = ref + r * DIN;
        float a0 = 0.f, a1 = 0.f, a2 = 0.f, a3 = 0.f;
        #pragma unroll
        for (int d = 0; d < DIN; d += 4) {
            a0 += row[d + 0] * wreg[d + 0];
            a1 += row[d + 1] * wreg[d + 1];
            a2 += row[d + 2] * wreg[d + 2];
            a3 += row[d + 3] * wreg[d + 3];
        }
        atomicAdd(&out[q * DOUT + lane], ((a0 + a1) + (a2 + a3)) * w);
    }
}

// =================================================================================

extern "C" void kernel_launch(void* const* d_in, const int* in_sizes, int n_in,
                              void* d_out, int out_size, void* d_ws, size_t ws_size,
                              hipStream_t stream) {
    const float* W        = (const float*)d_in[0];   // [K0, 64, 64]
    const float* ref      = (const float*)d_in[1];   // [N, 64]
    const int*   e_kernel = (const int*)d_in[2];     // [E]
    const int*   e_ref    = (const int*)d_in[3];     // [E]
    const int*   e_query  = (const int*)d_in[4];     // [E]
    const float* e_weight = (const float*)d_in[6];   // [E]

    const int K0 = in_sizes[0] / (DIN * DOUT);
    const int N  = in_sizes[1] / DIN;
    const int E  = in_sizes[2];
    const int M  = out_size / DOUT;
    const int KD = K0 * 64;
    const int NB = M / 256;          // coarse buckets

    float* out = (float*)d_out;

    // ---- plan A workspace carve ----
    size_t off = 0;
    auto alloc = [&](size_t bytes, size_t align) {
        off = (off + align - 1) / align * align;
        size_t r = off; off += bytes; return r;
    };
    size_t o_tmp     = alloc((size_t)E * 8, 16);
    size_t o_rec     = alloc((size_t)E * 8, 16);
    size_t o_qstart  = alloc((size_t)(M + 1) * 4, 4);
    size_t o_qcount  = alloc(256 * 4, 4);
    size_t o_gbase   = alloc(256 * 4, 4);
    size_t o_gcursor = alloc(256 * 4, 4);
    size_t o_wt      = alloc((size_t)K0 * 4096 * 2, 16);
    size_t o_T       = alloc((size_t)N * KD * 2, 16);
    size_t needA = off;

    bool planA_ok = (ws_size >= needA) && (M % 256 == 0) && (NB >= 1) && (NB <= 256) &&
                    (N % 64 == 0) && (N <= 65536) && (K0 <= 32);

    if (planA_ok) {
        char* ws = (char*)d_ws;
        uint2* tmp           = (uint2*)(ws + o_tmp);
        uint2* rec           = (uint2*)(ws + o_rec);
        int*  qstart         = (int*)(ws + o_qstart);
        int*  qcount         = (int*)(ws + o_qcount);
        int*  gbase          = (int*)(ws + o_gbase);
        int*  gcursor        = (int*)(ws + o_gcursor);
        unsigned short* Wt   = (unsigned short*)(ws + o_wt);
        unsigned short* T    = (unsigned short*)(ws + o_T);

        // conv_w also zeroes qcount (fused memset)
        conv_w_kernel<<<(K0 * 4096 + 255) / 256, 256, 0, stream>>>(W, Wt, K0 * 4096,
                                                                   qcount);
        p1_hist_kernel<<<512, 256, 0, stream>>>(e_query, E, qcount);
        p1_scan_kernel<<<1, 256, 0, stream>>>(qcount, gbase, gcursor, qstart, NB, M, E);
        p1_scatter_kernel<<<(E + 4095) / 4096, 256, 0, stream>>>(e_query, e_ref, e_kernel,
                                                                 e_weight, E, gcursor, tmp);
        p2_kernel<<<NB, 256, 0, stream>>>(tmp, gbase, qcount, rec, qstart);

        phaseA_kernel<<<N / 64, 256, 0, stream>>>(ref, Wt, T, K0, N);

        phaseB_kernel<<<M / 4, 256, 0, stream>>>(T, rec, qstart, out, N);
    } else {
        hipMemsetAsync(out, 0, (size_t)out_size * sizeof(float), stream);
        size_t needB = (size_t)(96 + E) * sizeof(int);
        if (ws_size >= needB) {
            int* ws_i   = (int*)d_ws;
            int* counts = ws_i;
            int* start  = ws_i + 32;
            int* cursor = ws_i + 64;
            int* sorted = ws_i + 96;
            hipMemsetAsync(counts, 0, 96 * sizeof(int), stream);
            hist_kernel<<<512, 256, 0, stream>>>(e_kernel, E, counts);
            scan_kernel<<<1, 64, 0, stream>>>(counts, K0, start, cursor);
            scatter_kernel<<<(E + 255) / 256, 256, 0, stream>>>(e_kernel, E, cursor, sorted);
            dim3 grid(64, K0);
            mp_bucket_kernel<<<grid, 256, 0, stream>>>(W, ref, e_ref, e_query, e_weight,
                                                       sorted, start, counts, out);
        }
    }
}